// Round 7
// baseline (196.106 us; speedup 1.0000x reference)
//
#include <hip/hip_runtime.h>
#include <stdint.h>

#define DEV __device__ __forceinline__

typedef short s8v __attribute__((ext_vector_type(8)));      // 8 x bf16 (as i16 payload)
typedef float f4v __attribute__((ext_vector_type(4)));      // MFMA accumulator
typedef unsigned short u16;

static constexpr float LAMBDA_INIT = 0.783605766531624464f;
static constexpr float OUT_SCALE   = 0.216394233468375536f;  // 1 - LAMBDA_INIT

DEV u16 f2bf(float f) {
    uint32_t u = __builtin_bit_cast(uint32_t, f);
    u += 0x7fffu + ((u >> 16) & 1u);          // round-to-nearest-even
    return (u16)(u >> 16);
}
DEV float bf2f(u16 v) {
    return __builtin_bit_cast(float, (uint32_t)v << 16);
}

// ---------------- f32 -> bf16 bulk convert (7 tensors, one launch) --------
__global__ __launch_bounds__(256)
void cvt_kernel(const float* __restrict__ q, const float* __restrict__ k,
                const float* __restrict__ v, const float* __restrict__ w0,
                const float* __restrict__ w1, const float* __restrict__ w2,
                const float* __restrict__ w3,
                u16* qo, u16* ko, u16* vo, u16* o0, u16* o1, u16* o2, u16* o3)
{
    int bid = blockIdx.x;
    const float* src; u16* dst; int base;
    if      (bid < 2048) { src = q;  dst = qo; base = bid * 2048; }
    else if (bid < 4096) { src = k;  dst = ko; base = (bid - 2048) * 2048; }
    else if (bid < 6144) { src = v;  dst = vo; base = (bid - 4096) * 2048; }
    else if (bid < 6656) { src = w0; dst = o0; base = (bid - 6144) * 2048; }
    else if (bid < 7168) { src = w1; dst = o1; base = (bid - 6656) * 2048; }
    else if (bid < 7680) { src = w2; dst = o2; base = (bid - 7168) * 2048; }
    else                 { src = w3; dst = o3; base = (bid - 7680) * 2048; }
    int i = base + threadIdx.x * 8;
    float4 a = *(const float4*)(src + i);
    float4 b = *(const float4*)(src + i + 4);
    u16 r[8] = { f2bf(a.x), f2bf(a.y), f2bf(a.z), f2bf(a.w),
                 f2bf(b.x), f2bf(b.y), f2bf(b.z), f2bf(b.w) };
    *(s8v*)(dst + i) = *(const s8v*)r;
}

// ---------------- GEMM: C[M,N-tile] = A[M,K]bf16 @ W[N,K]bf16^T + bias -----
template<int OUT_MODE>
__global__ __launch_bounds__(256)
void gemm128(const u16* __restrict__ A, const u16* __restrict__ W,
             const float* __restrict__ bias, void* __restrict__ Cp)
{
    constexpr int K = 1024;
    __shared__ __align__(16) char smem[OUT_MODE == 2 ? 32768 : 24576];
    const int m0 = blockIdx.x * 128, n0 = blockIdx.y * 64;
    const int t = threadIdx.x, lane = t & 63, wave = t >> 6;
    const int l15 = lane & 15, g = lane >> 4;

    f4v acc[2][4] = {};

    for (int k0 = 0; k0 < K; k0 += 64) {
#pragma unroll
        for (int i = 0; i < 4; ++i) {            // A: 16KB
            int idx = t + i * 256, row = idx >> 3, piece = idx & 7;
            s8v v = *(const s8v*)(A + (size_t)(m0 + row) * K + k0 + piece * 8);
            *(s8v*)(smem + row * 128 + ((piece * 16) ^ ((row & 7) << 4))) = v;
        }
#pragma unroll
        for (int i = 0; i < 2; ++i) {            // B: 8KB
            int idx = t + i * 256, row = idx >> 3, piece = idx & 7;
            s8v v = *(const s8v*)(W + (size_t)(n0 + row) * K + k0 + piece * 8);
            *(s8v*)(smem + 16384 + row * 128 + ((piece * 16) ^ ((row & 7) << 4))) = v;
        }
        __syncthreads();
#pragma unroll
        for (int ks = 0; ks < 2; ++ks) {
            s8v af[2], bf4[4];
#pragma unroll
            for (int mt = 0; mt < 2; ++mt) {
                int row = wave * 32 + mt * 16 + l15;
                af[mt] = *(const s8v*)(smem + row * 128 + ((ks * 64 + g * 16) ^ ((l15 & 7) << 4)));
            }
#pragma unroll
            for (int nt = 0; nt < 4; ++nt) {
                int row = nt * 16 + l15;
                bf4[nt] = *(const s8v*)(smem + 16384 + row * 128 + ((ks * 64 + g * 16) ^ ((l15 & 7) << 4)));
            }
#pragma unroll
            for (int mt = 0; mt < 2; ++mt)
#pragma unroll
                for (int nt = 0; nt < 4; ++nt)
                    acc[mt][nt] = __builtin_amdgcn_mfma_f32_16x16x32_bf16(af[mt], bf4[nt], acc[mt][nt], 0, 0, 0);
        }
        __syncthreads();
    }

    float bv[4];
#pragma unroll
    for (int nt = 0; nt < 4; ++nt) bv[nt] = bias[n0 + nt * 16 + l15];

    if (OUT_MODE == 0) {
        u16* rep = (u16*)smem;                    // [128][64]
#pragma unroll
        for (int mt = 0; mt < 2; ++mt)
#pragma unroll
            for (int nt = 0; nt < 4; ++nt)
#pragma unroll
                for (int r = 0; r < 4; ++r)
                    rep[(wave * 32 + mt * 16 + g * 4 + r) * 64 + nt * 16 + l15] = f2bf(acc[mt][nt][r] + bv[nt]);
        __syncthreads();
        u16* C = (u16*)Cp;
#pragma unroll
        for (int j = 0; j < 4; ++j) {
            int m = j * 32 + (t >> 3), chunk = t & 7;
            s8v v = *(const s8v*)(smem + m * 128 + chunk * 16);
            *(s8v*)(C + (size_t)(m0 + m) * 1024 + n0 + chunk * 8) = v;
        }
    } else if (OUT_MODE == 1) {
        u16* LT = (u16*)smem;                     // [64 n][136]
#pragma unroll
        for (int mt = 0; mt < 2; ++mt)
#pragma unroll
            for (int nt = 0; nt < 4; ++nt)
#pragma unroll
                for (int r = 0; r < 4; ++r)
                    LT[(nt * 16 + l15) * 136 + wave * 32 + mt * 16 + g * 4 + r] = f2bf(acc[mt][nt][r] + bv[nt]);
        __syncthreads();
        u16* C = (u16*)Cp;
        const int b = m0 >> 11, s0 = m0 & 2047;
#pragma unroll
        for (int j = 0; j < 4; ++j) {
            int n = j * 16 + (t >> 4), chunk = t & 15;
            s8v v = *(const s8v*)(smem + n * 272 + chunk * 16);
            *(s8v*)(C + ((size_t)b * 1024 + n0 + n) * 2048 + s0 + chunk * 8) = v;
        }
    } else {
        float* rep = (float*)smem;                // [128][64] f32 = 32KB
#pragma unroll
        for (int mt = 0; mt < 2; ++mt)
#pragma unroll
            for (int nt = 0; nt < 4; ++nt)
#pragma unroll
                for (int r = 0; r < 4; ++r)
                    rep[(wave * 32 + mt * 16 + g * 4 + r) * 64 + nt * 16 + l15] = acc[mt][nt][r] + bv[nt];
        __syncthreads();
        float* C = (float*)Cp;
#pragma unroll
        for (int j = 0; j < 8; ++j) {
            int m = j * 16 + (t >> 4), c4 = t & 15;
            float4 v = *(const float4*)(smem + m * 256 + c4 * 16);
            *(float4*)(C + (size_t)(m0 + m) * 1024 + n0 + c4 * 4) = v;
        }
    }
}

// ---------------- attention pass 1: per-slice exp row-sums ------------------
// 2048 blocks = b(2) x h(8) x qt(32) x sl(4); 256 thr = 4 waves (16 q-rows each).
// Block sums exp(s/8) over kv [sl*512, sl*512+512); psum[(bh,q)*8 + sub*4 + sl].
__global__ __launch_bounds__(256, 4)
void attn_sum(const u16* __restrict__ Qb, const u16* __restrict__ Kb,
              float* __restrict__ psum)
{
    constexpr int S = 2048, D = 1024;
    __shared__ __align__(16) char smem[16384];   // [2 sub][64 kv][128B] swizzled
    const int bid0 = blockIdx.x;
    const int bid = (bid0 & 7) * 256 + (bid0 >> 3);   // XCD-chunked swizzle
    const int sl = bid & 3, qt = (bid >> 2) & 31, h = (bid >> 7) & 7, b = bid >> 10;
    const int t = threadIdx.x, lane = t & 63, qw = t >> 6;
    const int l15 = lane & 15, g = lane >> 4;
    const int wrow0 = qt * 64 + qw * 16;

    const u16* Qbase = Qb + ((size_t)b * S + wrow0 + l15) * D + h * 128;
    s8v q1[2], q2[2];
#pragma unroll
    for (int ks = 0; ks < 2; ++ks) {
        q1[ks] = *(const s8v*)(Qbase + ks * 32 + g * 8);
        q2[ks] = *(const s8v*)(Qbase + 64 + ks * 32 + g * 8);
    }
    const u16* Ksrc = Kb + (size_t)b * S * D + (size_t)(sl * 512) * D + h * 128;
    const int swz = (l15 & 7) << 4;

    float t1a[4] = {}, t2a[4] = {};
    s8v kreg[4];
    // prologue: stage tile 0
#pragma unroll
    for (int i = 0; i < 4; ++i) {
        int idx = t + i * 256, row = idx >> 4, piece = idx & 15;
        kreg[i] = *(const s8v*)(Ksrc + (size_t)row * D + piece * 8);
    }
#pragma unroll
    for (int i = 0; i < 4; ++i) {
        int idx = t + i * 256, row = idx >> 4, piece = idx & 15;
        int sub = piece >> 3, colB = (piece & 7) * 16;
        *(s8v*)(smem + sub * 8192 + row * 128 + (colB ^ ((row & 7) << 4))) = kreg[i];
    }

    for (int kt = 0; kt < 8; ++kt) {
        if (kt < 7) {   // issue next-tile loads early (hidden under compute)
            const u16* src = Ksrc + (size_t)(kt + 1) * 64 * D;
#pragma unroll
            for (int i = 0; i < 4; ++i) {
                int idx = t + i * 256, row = idx >> 4, piece = idx & 15;
                kreg[i] = *(const s8v*)(src + (size_t)row * D + piece * 8);
            }
        }
        __syncthreads();   // staged tile visible
        f4v s1[4] = {}, s2[4] = {};
        __builtin_amdgcn_s_setprio(1);
#pragma unroll
        for (int nt = 0; nt < 4; ++nt)
#pragma unroll
            for (int ks = 0; ks < 2; ++ks) {
                int ro = (nt * 16 + l15) * 128 + ((ks * 64 + g * 16) ^ swz);
                s1[nt] = __builtin_amdgcn_mfma_f32_16x16x32_bf16(q1[ks], *(const s8v*)(smem + ro), s1[nt], 0, 0, 0);
                s2[nt] = __builtin_amdgcn_mfma_f32_16x16x32_bf16(q2[ks], *(const s8v*)(smem + 8192 + ro), s2[nt], 0, 0, 0);
            }
        __builtin_amdgcn_s_setprio(0);
#pragma unroll
        for (int nt = 0; nt < 4; ++nt)
#pragma unroll
            for (int r = 0; r < 4; ++r) {
                t1a[r] += __expf(s1[nt][r] * 0.125f);
                t2a[r] += __expf(s2[nt][r] * 0.125f);
            }
        __syncthreads();   // readers done
        if (kt < 7) {
#pragma unroll
            for (int i = 0; i < 4; ++i) {
                int idx = t + i * 256, row = idx >> 4, piece = idx & 15;
                int sub = piece >> 3, colB = (piece & 7) * 16;
                *(s8v*)(smem + sub * 8192 + row * 128 + (colB ^ ((row & 7) << 4))) = kreg[i];
            }
        }
    }

    // cross-lane reduce over the 16-lane q-row group, then write partials
#pragma unroll
    for (int r = 0; r < 4; ++r) {
#pragma unroll
        for (int off = 1; off < 16; off <<= 1) {
            t1a[r] += __shfl_xor(t1a[r], off);
            t2a[r] += __shfl_xor(t2a[r], off);
        }
    }
    if (l15 == 0) {
        float* pp = psum + (size_t)(((b * 8 + h) * 2048) + wrow0 + g * 4) * 8;
#pragma unroll
        for (int r = 0; r < 4; ++r) {
            pp[r * 8 + sl]     = t1a[r];
            pp[r * 8 + 4 + sl] = t2a[r];
        }
    }
}

// ---------------- attention pass 2: aw + PV + RMS-norm ----------------------
// 512 blocks = b(2) x h(8) x qtile(32); 8 waves (512 thr).
// wave w: qw = w>>1 owns 16 q-rows; kw = w&1 owns the kw-th 32-col kv half.
__global__ __launch_bounds__(512, 4)
void attn_kernel(const u16* __restrict__ Qb, const u16* __restrict__ Kb,
                 const u16* __restrict__ Vt, const float* __restrict__ psum,
                 const float* __restrict__ lq1, const float* __restrict__ lk1,
                 const float* __restrict__ lq2, const float* __restrict__ lk2,
                 const float* __restrict__ subw, float* __restrict__ aw,
                 u16* __restrict__ an)
{
    constexpr int S = 2048, D = 1024;
    __shared__ __align__(16) char smem[74752];
    // Kbuf0 @0 (16KB) | Vbuf0 @16384 (16KB) | Kbuf1 @32768 | Vbuf1 @49152
    // P @65536 ([64][72] u16 = 9216B) | Po (epilogue) overlays @0 (32KB)
    const int bid0 = blockIdx.x;
    const int bid = (bid0 & 7) * 64 + (bid0 >> 3);   // XCD-chunked swizzle
    const int qt = bid & 31, h = (bid >> 5) & 7, b = bid >> 8;
    const int t = threadIdx.x, lane = t & 63, w = t >> 6;
    const int qw = w >> 1, kw = w & 1;
    const int l15 = lane & 15, g = lane >> 4;
    const int qrow0 = qt * 64, wrow0 = qrow0 + qw * 16;

    short* P  = (short*)(smem + 65536);
    float* Po = (float*)smem;             // [64][128] epilogue overlay

    // lambda (computed redundantly per block)
    float lam;
    {
        float p1 = lq1[lane] * lk1[lane], p2 = lq2[lane] * lk2[lane];
#pragma unroll
        for (int off = 1; off < 64; off <<= 1) {
            p1 += __shfl_xor(p1, off);
            p2 += __shfl_xor(p2, off);
        }
        lam = expf(p1) - expf(p2) + LAMBDA_INIT;
    }

    const u16* Qbase = Qb + ((size_t)b * S + wrow0 + l15) * D + h * 128;
    s8v q1[2], q2[2];
#pragma unroll
    for (int ks = 0; ks < 2; ++ks) {
        q1[ks] = *(const s8v*)(Qbase + ks * 32 + g * 8);
        q2[ks] = *(const s8v*)(Qbase + 64 + ks * 32 + g * 8);
    }
    const u16* Ksrc = Kb + (size_t)b * S * D + h * 128;
    const u16* Vsrc = Vt + ((size_t)b * 1024 + h * 128) * 2048;
    const int swz = (l15 & 7) << 4;

    // il from psum partials (fixed-order sum -> deterministic)
    float il1[4], il2[4];
    {
        const float* pp = psum + (size_t)(((b * 8 + h) * 2048) + wrow0 + g * 4) * 8;
#pragma unroll
        for (int r = 0; r < 4; ++r) {
            float4 a = *(const float4*)(pp + r * 8);
            float4 c = *(const float4*)(pp + r * 8 + 4);
            il1[r] = 1.f / ((a.x + a.y) + (a.z + a.w));
            il2[r] = 1.f / ((c.x + c.y) + (c.z + c.w));
        }
    }

    // prologue: stage kt0 into buf0; load kt1 into regs
    s8v kreg[2], vreg[2];
#pragma unroll
    for (int i = 0; i < 2; ++i) {
        int idx = t + i * 512;
        { int row = idx >> 4, piece = idx & 15;
          kreg[i] = *(const s8v*)(Ksrc + (size_t)row * D + piece * 8); }
        { int dd = idx >> 3, piece = idx & 7;
          vreg[i] = *(const s8v*)(Vsrc + (size_t)dd * 2048 + piece * 8); }
    }
#pragma unroll
    for (int i = 0; i < 2; ++i) {
        int idx = t + i * 512;
        { int row = idx >> 4, piece = idx & 15;
          int sub = piece >> 3, colB = (piece & 7) * 16;
          *(s8v*)(smem + sub * 8192 + row * 128 + (colB ^ ((row & 7) << 4))) = kreg[i]; }
        { int dd = idx >> 3, piece = idx & 7;
          *(s8v*)(smem + 16384 + dd * 128 + ((piece * 16) ^ ((dd & 7) << 4))) = vreg[i]; }
    }
#pragma unroll
    for (int i = 0; i < 2; ++i) {
        int idx = t + i * 512;
        { int row = idx >> 4, piece = idx & 15;
          kreg[i] = *(const s8v*)(Ksrc + (size_t)(64 + row) * D + piece * 8); }
        { int dd = idx >> 3, piece = idx & 7;
          vreg[i] = *(const s8v*)(Vsrc + (size_t)dd * 2048 + 64 + piece * 8); }
    }
    __syncthreads();

    f4v po[8] = {};
    float* awb = aw + ((size_t)(b * 8 + h) * S + qrow0) * S;
    const int arow = lane >> 2, acol = kw * 32 + (lane & 3) * 8;

    for (int kt = 0; kt < 32; ++kt) {
        const int kv0 = kt * 64;
        char* cur = smem + (kt & 1) * 32768;
        char* nxt = smem + ((kt + 1) & 1) * 32768;
        if (kt < 31) {
#pragma unroll
            for (int i = 0; i < 2; ++i) {
                int idx = t + i * 512;
                { int row = idx >> 4, piece = idx & 15;
                  int sub = piece >> 3, colB = (piece & 7) * 16;
                  *(s8v*)(nxt + sub * 8192 + row * 128 + (colB ^ ((row & 7) << 4))) = kreg[i]; }
                { int dd = idx >> 3, piece = idx & 7;
                  *(s8v*)(nxt + 16384 + dd * 128 + ((piece * 16) ^ ((dd & 7) << 4))) = vreg[i]; }
            }
        }
        if (kt < 30) {
            const u16* ksp = Ksrc + (size_t)(kv0 + 128) * D;
            const u16* vsp = Vsrc + kv0 + 128;
#pragma unroll
            for (int i = 0; i < 2; ++i) {
                int idx = t + i * 512;
                { int row = idx >> 4, piece = idx & 15;
                  kreg[i] = *(const s8v*)(ksp + (size_t)row * D + piece * 8); }
                { int dd = idx >> 3, piece = idx & 7;
                  vreg[i] = *(const s8v*)(vsp + (size_t)dd * 2048 + piece * 8); }
            }
        }

        f4v s1[2] = {}, s2[2] = {};
        __builtin_amdgcn_s_setprio(1);
#pragma unroll
        for (int nt = 0; nt < 2; ++nt)
#pragma unroll
            for (int ks = 0; ks < 2; ++ks) {
                int ro = (kw * 32 + nt * 16 + l15) * 128 + ((ks * 64 + g * 16) ^ swz);
                s1[nt] = __builtin_amdgcn_mfma_f32_16x16x32_bf16(q1[ks], *(const s8v*)(cur + ro), s1[nt], 0, 0, 0);
                s2[nt] = __builtin_amdgcn_mfma_f32_16x16x32_bf16(q2[ks], *(const s8v*)(cur + 8192 + ro), s2[nt], 0, 0, 0);
            }
        __builtin_amdgcn_s_setprio(0);
#pragma unroll
        for (int nt = 0; nt < 2; ++nt)
#pragma unroll
            for (int r = 0; r < 4; ++r) {
                float p1 = __expf(s1[nt][r] * 0.125f) * il1[r];
                float p2 = __expf(s2[nt][r] * 0.125f) * il2[r];
                P[(qw * 16 + g * 4 + r) * 72 + kw * 32 + nt * 16 + l15] = (short)f2bf(p1 - lam * p2);
            }
        // wave-local P: in-order DS pipe orders write->read within the wave
        s8v pf = *(const s8v*)(P + (qw * 16 + l15) * 72 + kw * 32 + g * 8);
        __builtin_amdgcn_s_setprio(1);
#pragma unroll
        for (int dn = 0; dn < 8; ++dn) {
            const s8v* vf = (const s8v*)(cur + 16384 + (dn * 16 + l15) * 128 + ((kw * 64 + g * 16) ^ swz));
            po[dn] = __builtin_amdgcn_mfma_f32_16x16x32_bf16(pf, *vf, po[dn], 0, 0, 0);
        }
        __builtin_amdgcn_s_setprio(0);
        // aw dump (wave-local rows/cols, bf16->f32 exact)
        {
            s8v a = *(const s8v*)(P + (qw * 16 + arow) * 72 + acol);
            float4 o0 = { bf2f((u16)a[0]), bf2f((u16)a[1]), bf2f((u16)a[2]), bf2f((u16)a[3]) };
            float4 o1 = { bf2f((u16)a[4]), bf2f((u16)a[5]), bf2f((u16)a[6]), bf2f((u16)a[7]) };
            float* dp = awb + (size_t)(qw * 16 + arow) * S + kv0 + acol;
            *(float4*)dp = o0;
            *(float4*)(dp + 4) = o1;
        }
        __syncthreads();
    }

    // ---- combine partial PV across kw pairs (Po overlays buf0) ----
    if (kw == 0) {
#pragma unroll
        for (int dn = 0; dn < 8; ++dn)
#pragma unroll
            for (int r = 0; r < 4; ++r)
                Po[(qw * 16 + g * 4 + r) * 128 + dn * 16 + l15] = po[dn][r];
    }
    __syncthreads();
    if (kw == 1) {
#pragma unroll
        for (int dn = 0; dn < 8; ++dn)
#pragma unroll
            for (int r = 0; r < 4; ++r)
                Po[(qw * 16 + g * 4 + r) * 128 + dn * 16 + l15] += po[dn][r];
    }
    __syncthreads();

    // ---- epilogue: RMS-norm over 128, * subln_w * (1-lambda_init) ----
    {
        const int row = t >> 3, c0 = (t & 7) * 16;
        float ss = 0.f;
#pragma unroll
        for (int j = 0; j < 4; ++j) {
            float4 v4 = *(const float4*)(Po + row * 128 + c0 + j * 4);
            ss += v4.x * v4.x + v4.y * v4.y + v4.z * v4.z + v4.w * v4.w;
        }
#pragma unroll
        for (int off = 1; off < 8; off <<= 1) ss += __shfl_xor(ss, off);
        float rs = rsqrtf(ss * (1.0f / 128.0f) + 1e-5f) * OUT_SCALE;
        u16* dst = an + ((size_t)b * S + qrow0 + row) * D + h * 128;
#pragma unroll
        for (int j = 0; j < 2; ++j) {
            u16 tmp[8];
#pragma unroll
            for (int e = 0; e < 8; ++e) {
                int c = c0 + j * 8 + e;
                tmp[e] = f2bf(Po[row * 128 + c] * rs * subw[c]);
            }
            *(s8v*)(dst + c0 + j * 8) = *(const s8v*)tmp;
        }
    }
}

extern "C" void kernel_launch(void* const* d_in, const int* in_sizes, int n_in,
                              void* d_out, int out_size, void* d_ws, size_t ws_size,
                              hipStream_t stream)
{
    const float* query = (const float*)d_in[0];
    const float* key   = (const float*)d_in[1];
    const float* value = (const float*)d_in[2];
    const float* wq_w  = (const float*)d_in[3];
    const float* wq_b  = (const float*)d_in[4];
    const float* wk_w  = (const float*)d_in[5];
    const float* wk_b  = (const float*)d_in[6];
    const float* wv_w  = (const float*)d_in[7];
    const float* wv_b  = (const float*)d_in[8];
    const float* fc_w  = (const float*)d_in[9];
    const float* fc_b  = (const float*)d_in[10];
    const float* lq1   = (const float*)d_in[11];
    const float* lk1   = (const float*)d_in[12];
    const float* lq2   = (const float*)d_in[13];
    const float* lk2   = (const float*)d_in[14];
    const float* subw  = (const float*)d_in[15];

    const size_t MB = 1024 * 1024;
    char* ws = (char*)d_ws;
    u16*   Qbf = (u16*)(ws);             // [2][2048][1024] bf16 proj out
    u16*   Kbf = (u16*)(ws + 8 * MB);
    u16*   Vtg = (u16*)(ws + 16 * MB);   // [2][1024][2048] bf16 (transposed)
    u16*   ANb = (u16*)(ws + 24 * MB);   // [4096][1024] bf16
    u16*   wqb = (u16*)(ws + 32 * MB);   // bf16 weights (wqb region reused as psum)
    u16*   wkb = (u16*)(ws + 34 * MB);
    u16*   wvb = (u16*)(ws + 36 * MB);
    u16*   fcb = (u16*)(ws + 38 * MB);
    float* psum = (float*)(ws + 32 * MB);  // [2*8*2048][8] f32 = 1 MB (after gemm Q consumed wqb)

    float* out0 = (float*)d_out;
    float* awp  = out0 + (size_t)4096 * 1024;
    // converted bf16 inputs parked in the aw output region (rewritten by attn later)
    u16* qx = (u16*)awp;
    u16* kx = qx + (size_t)4096 * 1024;
    u16* vx = kx + (size_t)4096 * 1024;

    cvt_kernel<<<dim3(8192), dim3(256), 0, stream>>>(query, key, value, wq_w, wk_w, wv_w, fc_w,
                                                     qx, kx, vx, wqb, wkb, wvb, fcb);
    dim3 grid(32, 16), blk(256);
    gemm128<0><<<grid, blk, 0, stream>>>(qx, wqb, wq_b, Qbf);
    gemm128<0><<<grid, blk, 0, stream>>>(kx, wkb, wk_b, Kbf);
    gemm128<1><<<grid, blk, 0, stream>>>(vx, wvb, wv_b, Vtg);
    attn_sum<<<dim3(2048), dim3(256), 0, stream>>>(Qbf, Kbf, psum);
    attn_kernel<<<dim3(512), dim3(512), 0, stream>>>(Qbf, Kbf, Vtg, psum, lq1, lk1, lq2, lk2,
                                                     subw, awp, ANb);
    gemm128<2><<<grid, blk, 0, stream>>>(ANb, fcb, fc_b, out0);
}

// Round 9
// 190.248 us; speedup vs baseline: 1.0308x; 1.0308x over previous
//
#include <hip/hip_runtime.h>
#include <stdint.h>

#define DEV __device__ __forceinline__

typedef short s8v __attribute__((ext_vector_type(8)));      // 8 x bf16 (as i16 payload)
typedef short s4v __attribute__((ext_vector_type(4)));      // 4 x bf16
typedef float f4v __attribute__((ext_vector_type(4)));      // MFMA accumulator / 16B store
typedef unsigned short u16;

static constexpr float LAMBDA_INIT = 0.783605766531624464f;
static constexpr float OUT_SCALE   = 0.216394233468375536f;  // 1 - LAMBDA_INIT

DEV u16 f2bf(float f) {
    uint32_t u = __builtin_bit_cast(uint32_t, f);
    u += 0x7fffu + ((u >> 16) & 1u);          // round-to-nearest-even
    return (u16)(u >> 16);
}
DEV float bf2f(u16 v) {
    return __builtin_bit_cast(float, (uint32_t)v << 16);
}

// ---------------- f32 -> bf16 bulk convert (7 tensors, one launch) --------
__global__ __launch_bounds__(256)
void cvt_kernel(const float* __restrict__ q, const float* __restrict__ k,
                const float* __restrict__ v, const float* __restrict__ w0,
                const float* __restrict__ w1, const float* __restrict__ w2,
                const float* __restrict__ w3,
                u16* qo, u16* ko, u16* vo, u16* o0, u16* o1, u16* o2, u16* o3)
{
    int bid = blockIdx.x;
    const float* src; u16* dst; int base;
    if      (bid < 2048) { src = q;  dst = qo; base = bid * 2048; }
    else if (bid < 4096) { src = k;  dst = ko; base = (bid - 2048) * 2048; }
    else if (bid < 6144) { src = v;  dst = vo; base = (bid - 4096) * 2048; }
    else if (bid < 6656) { src = w0; dst = o0; base = (bid - 6144) * 2048; }
    else if (bid < 7168) { src = w1; dst = o1; base = (bid - 6656) * 2048; }
    else if (bid < 7680) { src = w2; dst = o2; base = (bid - 7168) * 2048; }
    else                 { src = w3; dst = o3; base = (bid - 7680) * 2048; }
    int i = base + threadIdx.x * 8;
    float4 a = *(const float4*)(src + i);
    float4 b = *(const float4*)(src + i + 4);
    u16 r[8] = { f2bf(a.x), f2bf(a.y), f2bf(a.z), f2bf(a.w),
                 f2bf(b.x), f2bf(b.y), f2bf(b.z), f2bf(b.w) };
    *(s8v*)(dst + i) = *(const s8v*)r;
}

// ---------------- GEMM: C[M,N-tile] = A[M,K]bf16 @ W[N,K]bf16^T + bias -----
template<int OUT_MODE>
__global__ __launch_bounds__(256)
void gemm128(const u16* __restrict__ A, const u16* __restrict__ W,
             const float* __restrict__ bias, void* __restrict__ Cp)
{
    constexpr int K = 1024;
    __shared__ __align__(16) char smem[OUT_MODE == 2 ? 32768 : 24576];
    const int m0 = blockIdx.x * 128, n0 = blockIdx.y * 64;
    const int t = threadIdx.x, lane = t & 63, wave = t >> 6;
    const int l15 = lane & 15, g = lane >> 4;

    f4v acc[2][4] = {};

    for (int k0 = 0; k0 < K; k0 += 64) {
#pragma unroll
        for (int i = 0; i < 4; ++i) {            // A: 16KB
            int idx = t + i * 256, row = idx >> 3, piece = idx & 7;
            s8v v = *(const s8v*)(A + (size_t)(m0 + row) * K + k0 + piece * 8);
            *(s8v*)(smem + row * 128 + ((piece * 16) ^ ((row & 7) << 4))) = v;
        }
#pragma unroll
        for (int i = 0; i < 2; ++i) {            // B: 8KB
            int idx = t + i * 256, row = idx >> 3, piece = idx & 7;
            s8v v = *(const s8v*)(W + (size_t)(n0 + row) * K + k0 + piece * 8);
            *(s8v*)(smem + 16384 + row * 128 + ((piece * 16) ^ ((row & 7) << 4))) = v;
        }
        __syncthreads();
#pragma unroll
        for (int ks = 0; ks < 2; ++ks) {
            s8v af[2], bf4[4];
#pragma unroll
            for (int mt = 0; mt < 2; ++mt) {
                int row = wave * 32 + mt * 16 + l15;
                af[mt] = *(const s8v*)(smem + row * 128 + ((ks * 64 + g * 16) ^ ((l15 & 7) << 4)));
            }
#pragma unroll
            for (int nt = 0; nt < 4; ++nt) {
                int row = nt * 16 + l15;
                bf4[nt] = *(const s8v*)(smem + 16384 + row * 128 + ((ks * 64 + g * 16) ^ ((l15 & 7) << 4)));
            }
#pragma unroll
            for (int mt = 0; mt < 2; ++mt)
#pragma unroll
                for (int nt = 0; nt < 4; ++nt)
                    acc[mt][nt] = __builtin_amdgcn_mfma_f32_16x16x32_bf16(af[mt], bf4[nt], acc[mt][nt], 0, 0, 0);
        }
        __syncthreads();
    }

    float bv[4];
#pragma unroll
    for (int nt = 0; nt < 4; ++nt) bv[nt] = bias[n0 + nt * 16 + l15];

    if (OUT_MODE == 0) {
        u16* rep = (u16*)smem;                    // [128][64]
#pragma unroll
        for (int mt = 0; mt < 2; ++mt)
#pragma unroll
            for (int nt = 0; nt < 4; ++nt)
#pragma unroll
                for (int r = 0; r < 4; ++r)
                    rep[(wave * 32 + mt * 16 + g * 4 + r) * 64 + nt * 16 + l15] = f2bf(acc[mt][nt][r] + bv[nt]);
        __syncthreads();
        u16* C = (u16*)Cp;
#pragma unroll
        for (int j = 0; j < 4; ++j) {
            int m = j * 32 + (t >> 3), chunk = t & 7;
            s8v v = *(const s8v*)(smem + m * 128 + chunk * 16);
            *(s8v*)(C + (size_t)(m0 + m) * 1024 + n0 + chunk * 8) = v;
        }
    } else if (OUT_MODE == 1) {
        u16* LT = (u16*)smem;                     // [64 n][136]
#pragma unroll
        for (int mt = 0; mt < 2; ++mt)
#pragma unroll
            for (int nt = 0; nt < 4; ++nt)
#pragma unroll
                for (int r = 0; r < 4; ++r)
                    LT[(nt * 16 + l15) * 136 + wave * 32 + mt * 16 + g * 4 + r] = f2bf(acc[mt][nt][r] + bv[nt]);
        __syncthreads();
        u16* C = (u16*)Cp;
        const int b = m0 >> 11, s0 = m0 & 2047;
#pragma unroll
        for (int j = 0; j < 4; ++j) {
            int n = j * 16 + (t >> 4), chunk = t & 15;
            s8v v = *(const s8v*)(smem + n * 272 + chunk * 16);
            *(s8v*)(C + ((size_t)b * 1024 + n0 + n) * 2048 + s0 + chunk * 8) = v;
        }
    } else {
        float* rep = (float*)smem;                // [128][64] f32 = 32KB
#pragma unroll
        for (int mt = 0; mt < 2; ++mt)
#pragma unroll
            for (int nt = 0; nt < 4; ++nt)
#pragma unroll
                for (int r = 0; r < 4; ++r)
                    rep[(wave * 32 + mt * 16 + g * 4 + r) * 64 + nt * 16 + l15] = acc[mt][nt][r] + bv[nt];
        __syncthreads();
        float* C = (float*)Cp;
#pragma unroll
        for (int j = 0; j < 8; ++j) {
            int m = j * 16 + (t >> 4), c4 = t & 15;
            float4 v = *(const float4*)(smem + m * 256 + c4 * 16);
            *(float4*)(C + (size_t)(m0 + m) * 1024 + n0 + c4 * 4) = v;
        }
    }
}

// ---------------- attention pass 1: per-slice exp row-sums ------------------
// 2048 blocks = b(2) x h(8) x qt(32) x sl(4); 256 thr = 4 waves (16 q-rows each).
// Double-buffered K staging: 1 barrier per kt.
__global__ __launch_bounds__(256, 4)
void attn_sum(const u16* __restrict__ Qb, const u16* __restrict__ Kb,
              float* __restrict__ psum)
{
    constexpr int S = 2048, D = 1024;
    __shared__ __align__(16) char smem[32768];   // 2 x [2 sub][64 kv][128B] swizzled
    const int bid0 = blockIdx.x;
    const int bid = (bid0 & 7) * 256 + (bid0 >> 3);   // XCD-chunked swizzle
    const int sl = bid & 3, qt = (bid >> 2) & 31, h = (bid >> 7) & 7, b = bid >> 10;
    const int t = threadIdx.x, lane = t & 63, qw = t >> 6;
    const int l15 = lane & 15, g = lane >> 4;
    const int wrow0 = qt * 64 + qw * 16;

    const u16* Qbase = Qb + ((size_t)b * S + wrow0 + l15) * D + h * 128;
    s8v q1[2], q2[2];
#pragma unroll
    for (int ks = 0; ks < 2; ++ks) {
        q1[ks] = *(const s8v*)(Qbase + ks * 32 + g * 8);
        q2[ks] = *(const s8v*)(Qbase + 64 + ks * 32 + g * 8);
    }
    const u16* Ksrc = Kb + (size_t)b * S * D + (size_t)(sl * 512) * D + h * 128;
    const int swz = (l15 & 7) << 4;

    float t1a[4] = {}, t2a[4] = {};
    s8v kreg[4];
    // prologue: stage kt0 -> buf0; load kt1 regs
#pragma unroll
    for (int i = 0; i < 4; ++i) {
        int idx = t + i * 256, row = idx >> 4, piece = idx & 15;
        kreg[i] = *(const s8v*)(Ksrc + (size_t)row * D + piece * 8);
    }
#pragma unroll
    for (int i = 0; i < 4; ++i) {
        int idx = t + i * 256, row = idx >> 4, piece = idx & 15;
        int sub = piece >> 3, colB = (piece & 7) * 16;
        *(s8v*)(smem + sub * 8192 + row * 128 + (colB ^ ((row & 7) << 4))) = kreg[i];
    }
#pragma unroll
    for (int i = 0; i < 4; ++i) {
        int idx = t + i * 256, row = idx >> 4, piece = idx & 15;
        kreg[i] = *(const s8v*)(Ksrc + (size_t)(64 + row) * D + piece * 8);
    }
    __syncthreads();

    for (int kt = 0; kt < 8; ++kt) {
        char* cur = smem + (kt & 1) * 16384;
        char* nxt = smem + ((kt + 1) & 1) * 16384;
        if (kt < 7) {
#pragma unroll
            for (int i = 0; i < 4; ++i) {
                int idx = t + i * 256, row = idx >> 4, piece = idx & 15;
                int sub = piece >> 3, colB = (piece & 7) * 16;
                *(s8v*)(nxt + sub * 8192 + row * 128 + (colB ^ ((row & 7) << 4))) = kreg[i];
            }
        }
        if (kt < 6) {
            const u16* src = Ksrc + (size_t)(kt + 2) * 64 * D;
#pragma unroll
            for (int i = 0; i < 4; ++i) {
                int idx = t + i * 256, row = idx >> 4, piece = idx & 15;
                kreg[i] = *(const s8v*)(src + (size_t)row * D + piece * 8);
            }
        }
        f4v s1[4] = {}, s2[4] = {};
        __builtin_amdgcn_s_setprio(1);
#pragma unroll
        for (int nt = 0; nt < 4; ++nt)
#pragma unroll
            for (int ks = 0; ks < 2; ++ks) {
                int ro = (nt * 16 + l15) * 128 + ((ks * 64 + g * 16) ^ swz);
                s1[nt] = __builtin_amdgcn_mfma_f32_16x16x32_bf16(q1[ks], *(const s8v*)(cur + ro), s1[nt], 0, 0, 0);
                s2[nt] = __builtin_amdgcn_mfma_f32_16x16x32_bf16(q2[ks], *(const s8v*)(cur + 8192 + ro), s2[nt], 0, 0, 0);
            }
        __builtin_amdgcn_s_setprio(0);
#pragma unroll
        for (int nt = 0; nt < 4; ++nt)
#pragma unroll
            for (int r = 0; r < 4; ++r) {
                t1a[r] += __expf(s1[nt][r] * 0.125f);
                t2a[r] += __expf(s2[nt][r] * 0.125f);
            }
        __syncthreads();
    }

    // cross-lane reduce over the 16-lane q-row group, then write partials
#pragma unroll
    for (int r = 0; r < 4; ++r) {
#pragma unroll
        for (int off = 1; off < 16; off <<= 1) {
            t1a[r] += __shfl_xor(t1a[r], off);
            t2a[r] += __shfl_xor(t2a[r], off);
        }
    }
    if (l15 == 0) {
        float* pp = psum + (size_t)(((b * 8 + h) * 2048) + wrow0 + g * 4) * 8;
#pragma unroll
        for (int r = 0; r < 4; ++r) {
            pp[r * 8 + sl]     = t1a[r];
            pp[r * 8 + 4 + sl] = t2a[r];
        }
    }
}

// ---------------- attention pass 2: aw + PV + RMS-norm ----------------------
// 512 blocks = b(2) x h(8) x qtile(32); 8 waves (512 thr).
// wave w: qw = w>>1 owns 16 q-rows; kw = w&1 owns the kw-th 32-col kv half.
__global__ __launch_bounds__(512, 4)
void attn_kernel(const u16* __restrict__ Qb, const u16* __restrict__ Kb,
                 const u16* __restrict__ Vt, const float* __restrict__ psum,
                 const float* __restrict__ lq1, const float* __restrict__ lk1,
                 const float* __restrict__ lq2, const float* __restrict__ lk2,
                 const float* __restrict__ subw, float* __restrict__ aw,
                 u16* __restrict__ an)
{
    constexpr int S = 2048, D = 1024;
    __shared__ __align__(16) char smem[74752];
    // Kbuf0 @0 (16KB) | Vbuf0 @16384 (16KB) | Kbuf1 @32768 | Vbuf1 @49152
    // P @65536 ([64][72] u16 = 9216B) | Po (epilogue) overlays @0 (32KB)
    const int bid0 = blockIdx.x;
    const int bid = (bid0 & 7) * 64 + (bid0 >> 3);   // XCD-chunked swizzle
    const int qt = bid & 31, h = (bid >> 5) & 7, b = bid >> 8;
    const int t = threadIdx.x, lane = t & 63, w = t >> 6;
    const int qw = w >> 1, kw = w & 1;
    const int l15 = lane & 15, g = lane >> 4;
    const int qrow0 = qt * 64, wrow0 = qrow0 + qw * 16;

    short* P  = (short*)(smem + 65536);
    float* Po = (float*)smem;             // [64][128] epilogue overlay

    // lambda (computed redundantly per block)
    float lam;
    {
        float p1 = lq1[lane] * lk1[lane], p2 = lq2[lane] * lk2[lane];
#pragma unroll
        for (int off = 1; off < 64; off <<= 1) {
            p1 += __shfl_xor(p1, off);
            p2 += __shfl_xor(p2, off);
        }
        lam = expf(p1) - expf(p2) + LAMBDA_INIT;
    }

    const u16* Qbase = Qb + ((size_t)b * S + wrow0 + l15) * D + h * 128;
    s8v q1[2], q2[2];
#pragma unroll
    for (int ks = 0; ks < 2; ++ks) {
        q1[ks] = *(const s8v*)(Qbase + ks * 32 + g * 8);
        q2[ks] = *(const s8v*)(Qbase + 64 + ks * 32 + g * 8);
    }
    const u16* Ksrc = Kb + (size_t)b * S * D + h * 128;
    const u16* Vsrc = Vt + ((size_t)b * 1024 + h * 128) * 2048;
    const int swz = (l15 & 7) << 4;

    // il from psum partials (fixed-order sum -> deterministic)
    float il1[4], il2[4];
    {
        const float* pp = psum + (size_t)(((b * 8 + h) * 2048) + wrow0 + g * 4) * 8;
#pragma unroll
        for (int r = 0; r < 4; ++r) {
            float4 a = *(const float4*)(pp + r * 8);
            float4 c = *(const float4*)(pp + r * 8 + 4);
            il1[r] = 1.f / ((a.x + a.y) + (a.z + a.w));
            il2[r] = 1.f / ((c.x + c.y) + (c.z + c.w));
        }
    }

    // prologue: stage kt0 into buf0; load kt1 into regs
    s8v kreg[2], vreg[2];
#pragma unroll
    for (int i = 0; i < 2; ++i) {
        int idx = t + i * 512;
        { int row = idx >> 4, piece = idx & 15;
          kreg[i] = *(const s8v*)(Ksrc + (size_t)row * D + piece * 8); }
        { int dd = idx >> 3, piece = idx & 7;
          vreg[i] = *(const s8v*)(Vsrc + (size_t)dd * 2048 + piece * 8); }
    }
#pragma unroll
    for (int i = 0; i < 2; ++i) {
        int idx = t + i * 512;
        { int row = idx >> 4, piece = idx & 15;
          int sub = piece >> 3, colB = (piece & 7) * 16;
          *(s8v*)(smem + sub * 8192 + row * 128 + (colB ^ ((row & 7) << 4))) = kreg[i]; }
        { int dd = idx >> 3, piece = idx & 7;
          *(s8v*)(smem + 16384 + dd * 128 + ((piece * 16) ^ ((dd & 7) << 4))) = vreg[i]; }
    }
#pragma unroll
    for (int i = 0; i < 2; ++i) {
        int idx = t + i * 512;
        { int row = idx >> 4, piece = idx & 15;
          kreg[i] = *(const s8v*)(Ksrc + (size_t)(64 + row) * D + piece * 8); }
        { int dd = idx >> 3, piece = idx & 7;
          vreg[i] = *(const s8v*)(Vsrc + (size_t)dd * 2048 + 64 + piece * 8); }
    }
    __syncthreads();

    f4v po[8] = {};
    float* awb = aw + ((size_t)(b * 8 + h) * S + qrow0) * S;
    const int drl = lane >> 3;            // 0..7 row within 8-row half
    const int dc4 = (lane & 7) * 4;       // float col within 32-col strip

    for (int kt = 0; kt < 32; ++kt) {
        const int kv0 = kt * 64;
        char* cur = smem + (kt & 1) * 32768;
        char* nxt = smem + ((kt + 1) & 1) * 32768;
        if (kt < 31) {
#pragma unroll
            for (int i = 0; i < 2; ++i) {
                int idx = t + i * 512;
                { int row = idx >> 4, piece = idx & 15;
                  int sub = piece >> 3, colB = (piece & 7) * 16;
                  *(s8v*)(nxt + sub * 8192 + row * 128 + (colB ^ ((row & 7) << 4))) = kreg[i]; }
                { int dd = idx >> 3, piece = idx & 7;
                  *(s8v*)(nxt + 16384 + dd * 128 + ((piece * 16) ^ ((dd & 7) << 4))) = vreg[i]; }
            }
        }
        if (kt < 30) {
            const u16* ksp = Ksrc + (size_t)(kv0 + 128) * D;
            const u16* vsp = Vsrc + kv0 + 128;
#pragma unroll
            for (int i = 0; i < 2; ++i) {
                int idx = t + i * 512;
                { int row = idx >> 4, piece = idx & 15;
                  kreg[i] = *(const s8v*)(ksp + (size_t)row * D + piece * 8); }
                { int dd = idx >> 3, piece = idx & 7;
                  vreg[i] = *(const s8v*)(vsp + (size_t)dd * 2048 + piece * 8); }
            }
        }

        f4v s1[2] = {}, s2[2] = {};
        __builtin_amdgcn_s_setprio(1);
#pragma unroll
        for (int nt = 0; nt < 2; ++nt)
#pragma unroll
            for (int ks = 0; ks < 2; ++ks) {
                int ro = (kw * 32 + nt * 16 + l15) * 128 + ((ks * 64 + g * 16) ^ swz);
                s1[nt] = __builtin_amdgcn_mfma_f32_16x16x32_bf16(q1[ks], *(const s8v*)(cur + ro), s1[nt], 0, 0, 0);
                s2[nt] = __builtin_amdgcn_mfma_f32_16x16x32_bf16(q2[ks], *(const s8v*)(cur + 8192 + ro), s2[nt], 0, 0, 0);
            }
        __builtin_amdgcn_s_setprio(0);
#pragma unroll
        for (int nt = 0; nt < 2; ++nt)
#pragma unroll
            for (int r = 0; r < 4; ++r) {
                float p1 = __expf(s1[nt][r] * 0.125f) * il1[r];
                float p2 = __expf(s2[nt][r] * 0.125f) * il2[r];
                P[(qw * 16 + g * 4 + r) * 72 + kw * 32 + nt * 16 + l15] = (short)f2bf(p1 - lam * p2);
            }

        // aw dump first (stores overlap the PV MFMAs below).
        // wave-local: rows qw*16..+16, cols kw*32..+32; per instr 8 rows x
        // fully-contiguous 128B runs; non-temporal (don't pollute L2).
#pragma unroll
        for (int half = 0; half < 2; ++half) {
            int row = qw * 16 + half * 8 + drl;
            s4v pv = *(const s4v*)(P + row * 72 + kw * 32 + dc4);
            f4v o = { bf2f((u16)pv.x), bf2f((u16)pv.y), bf2f((u16)pv.z), bf2f((u16)pv.w) };
            __builtin_nontemporal_store(o, (f4v*)(awb + (size_t)row * S + kv0 + kw * 32 + dc4));
        }

        // wave-local P: in-order DS pipe orders write->read within the wave
        s8v pf = *(const s8v*)(P + (qw * 16 + l15) * 72 + kw * 32 + g * 8);
        __builtin_amdgcn_s_setprio(1);
#pragma unroll
        for (int dn = 0; dn < 8; ++dn) {
            const s8v* vf = (const s8v*)(cur + 16384 + (dn * 16 + l15) * 128 + ((kw * 64 + g * 16) ^ swz));
            po[dn] = __builtin_amdgcn_mfma_f32_16x16x32_bf16(pf, *vf, po[dn], 0, 0, 0);
        }
        __builtin_amdgcn_s_setprio(0);
        __syncthreads();
    }

    // ---- combine partial PV across kw pairs (Po overlays buf0) ----
    if (kw == 0) {
#pragma unroll
        for (int dn = 0; dn < 8; ++dn)
#pragma unroll
            for (int r = 0; r < 4; ++r)
                Po[(qw * 16 + g * 4 + r) * 128 + dn * 16 + l15] = po[dn][r];
    }
    __syncthreads();
    if (kw == 1) {
#pragma unroll
        for (int dn = 0; dn < 8; ++dn)
#pragma unroll
            for (int r = 0; r < 4; ++r)
                Po[(qw * 16 + g * 4 + r) * 128 + dn * 16 + l15] += po[dn][r];
    }
    __syncthreads();

    // ---- epilogue: RMS-norm over 128, * subln_w * (1-lambda_init) ----
    {
        const int row = t >> 3, c0 = (t & 7) * 16;
        float ss = 0.f;
#pragma unroll
        for (int j = 0; j < 4; ++j) {
            float4 v4 = *(const float4*)(Po + row * 128 + c0 + j * 4);
            ss += v4.x * v4.x + v4.y * v4.y + v4.z * v4.z + v4.w * v4.w;
        }
#pragma unroll
        for (int off = 1; off < 8; off <<= 1) ss += __shfl_xor(ss, off);
        float rs = rsqrtf(ss * (1.0f / 128.0f) + 1e-5f) * OUT_SCALE;
        u16* dst = an + ((size_t)b * S + qrow0 + row) * D + h * 128;
#pragma unroll
        for (int j = 0; j < 2; ++j) {
            u16 tmp[8];
#pragma unroll
            for (int e = 0; e < 8; ++e) {
                int c = c0 + j * 8 + e;
                tmp[e] = f2bf(Po[row * 128 + c] * rs * subw[c]);
            }
            *(s8v*)(dst + c0 + j * 8) = *(const s8v*)tmp;
        }
    }
}

extern "C" void kernel_launch(void* const* d_in, const int* in_sizes, int n_in,
                              void* d_out, int out_size, void* d_ws, size_t ws_size,
                              hipStream_t stream)
{
    const float* query = (const float*)d_in[0];
    const float* key   = (const float*)d_in[1];
    const float* value = (const float*)d_in[2];
    const float* wq_w  = (const float*)d_in[3];
    const float* wq_b  = (const float*)d_in[4];
    const float* wk_w  = (const float*)d_in[5];
    const float* wk_b  = (const float*)d_in[6];
    const float* wv_w  = (const float*)d_in[7];
    const float* wv_b  = (const float*)d_in[8];
    const float* fc_w  = (const float*)d_in[9];
    const float* fc_b  = (const float*)d_in[10];
    const float* lq1   = (const float*)d_in[11];
    const float* lk1   = (const float*)d_in[12];
    const float* lq2   = (const float*)d_in[13];
    const float* lk2   = (const float*)d_in[14];
    const float* subw  = (const float*)d_in[15];

    const size_t MB = 1024 * 1024;
    char* ws = (char*)d_ws;
    u16*   Qbf = (u16*)(ws);             // [2][2048][1024] bf16 proj out
    u16*   Kbf = (u16*)(ws + 8 * MB);
    u16*   Vtg = (u16*)(ws + 16 * MB);   // [2][1024][2048] bf16 (transposed)
    u16*   ANb = (u16*)(ws + 24 * MB);   // [4096][1024] bf16
    u16*   wqb = (u16*)(ws + 32 * MB);   // bf16 weights (wqb region reused as psum)
    u16*   wkb = (u16*)(ws + 34 * MB);
    u16*   wvb = (u16*)(ws + 36 * MB);
    u16*   fcb = (u16*)(ws + 38 * MB);
    float* psum = (float*)(ws + 32 * MB);  // [2*8*2048][8] f32 = 1 MB (after gemm Q consumed wqb)

    float* out0 = (float*)d_out;
    float* awp  = out0 + (size_t)4096 * 1024;
    // converted bf16 inputs parked in the aw output region (rewritten by attn later)
    u16* qx = (u16*)awp;
    u16* kx = qx + (size_t)4096 * 1024;
    u16* vx = kx + (size_t)4096 * 1024;

    cvt_kernel<<<dim3(8192), dim3(256), 0, stream>>>(query, key, value, wq_w, wk_w, wv_w, fc_w,
                                                     qx, kx, vx, wqb, wkb, wvb, fcb);
    dim3 grid(32, 16), blk(256);
    gemm128<0><<<grid, blk, 0, stream>>>(qx, wqb, wq_b, Qbf);
    gemm128<0><<<grid, blk, 0, stream>>>(kx, wkb, wk_b, Kbf);
    gemm128<1><<<grid, blk, 0, stream>>>(vx, wvb, wv_b, Vtg);
    attn_sum<<<dim3(2048), dim3(256), 0, stream>>>(Qbf, Kbf, psum);
    attn_kernel<<<dim3(512), dim3(512), 0, stream>>>(Qbf, Kbf, Vtg, psum, lq1, lk1, lq2, lk2,
                                                     subw, awp, ANb);
    gemm128<2><<<grid, blk, 0, stream>>>(ANb, fcb, fc_b, out0);
}